// Round 9
// baseline (73.752 us; speedup 1.0000x reference)
//
#include <hip/hip_runtime.h>
#include <hip/hip_bf16.h>

// BQQ dims: P=2, J=32, K=32, M=128, L=16, N=128; B=512
// Restructured (no W materialization):
//   out[b, j*128+m] = s * ( sum_k [ sum_pl Ye[m,pl]*T_raw[b,pl] + Sx[b,k]*e[m] ] ) + bias
//   T_raw[b,l](p,j,k) = sum_n Xi[b,kn]*Zsign[l,n]          (MFMA, exact ints in f32)
//   Ye[m,pl] = c0_p*Ysign[m,l] + az_p   (c0=A0*Ysc*Zsc, az=A2*Zsc -> folds out3)
//   e[m] = sum_p (A1*Ysc)*Ysum_sign[p,m] + sum_p A3        (folds out2+out4)
typedef __attribute__((ext_vector_type(4))) float f32x4;
typedef __attribute__((ext_vector_type(8))) short bf16x8;

#define GLOBAL_AS __attribute__((address_space(1)))
#define LDS_AS __attribute__((address_space(3)))

static __device__ __forceinline__ unsigned short f2bf(float f) {
  __hip_bfloat16 h = __float2bfloat16(f);
  return __builtin_bit_cast(unsigned short, h);
}
static __device__ __forceinline__ void load_lds16(const void* g, void* l) {
  __builtin_amdgcn_global_load_lds((GLOBAL_AS void*)g, (LDS_AS void*)l, 16, 0, 0);
}

// ---------------- 1) per-block min/max of input (2M f32), 256 blocks ----------------
__global__ __launch_bounds__(256) void k_minmax_part(const float* __restrict__ x,
                                                     float* __restrict__ part) {
  int tid = blockIdx.x * 256 + threadIdx.x;
  const float4* xv = (const float4*)x;
  float mn = 3.4e38f, mx = -3.4e38f;
#pragma unroll
  for (int rep = 0; rep < 8; ++rep) {
    float4 v = xv[tid + rep * 65536];
    mn = fminf(mn, fminf(fminf(v.x, v.y), fminf(v.z, v.w)));
    mx = fmaxf(mx, fmaxf(fmaxf(v.x, v.y), fmaxf(v.z, v.w)));
  }
#pragma unroll
  for (int o = 32; o > 0; o >>= 1) {
    mn = fminf(mn, __shfl_down(mn, o));
    mx = fmaxf(mx, __shfl_down(mx, o));
  }
  __shared__ float smn[4], smx[4];
  int lane = threadIdx.x & 63, w = threadIdx.x >> 6;
  if (lane == 0) { smn[w] = mn; smx[w] = mx; }
  __syncthreads();
  if (threadIdx.x == 0) {
    mn = fminf(fminf(smn[0], smn[1]), fminf(smn[2], smn[3]));
    mx = fmaxf(fmaxf(smx[0], smx[1]), fmaxf(smx[2], smx[3]));
    part[2 * blockIdx.x] = mn;
    part[2 * blockIdx.x + 1] = mx;
  }
}

// ---------------- 2) quantize + Sx row-sums; 2048 blocks ----------------
// block qb: elements [qb*1024, +1024) => b = qb>>2, k = (qb&3)*8 + (t>>5), n0=(t&31)*4
__global__ __launch_bounds__(256) void k_quant(const float* __restrict__ x,
                                               const float* __restrict__ part,
                                               float* __restrict__ scl,
                                               unsigned short* __restrict__ xq,
                                               float* __restrict__ Sx) {
  const int t = threadIdx.x, qb = blockIdx.x;
  float2 v2 = ((const float2*)part)[t];  // 512 partials
  float mn = v2.x, mx = v2.y;
#pragma unroll
  for (int o = 32; o > 0; o >>= 1) {
    mn = fminf(mn, __shfl_down(mn, o));
    mx = fmaxf(mx, __shfl_down(mx, o));
  }
  __shared__ float smn[4], smx[4], ssc[1];
  int lane = t & 63, w = t >> 6;
  if (lane == 0) { smn[w] = mn; smx[w] = mx; }
  __syncthreads();
  if (t == 0) {
    mn = fminf(fminf(smn[0], smn[1]), fminf(smn[2], smn[3]));
    mx = fmaxf(fmaxf(smx[0], smx[1]), fmaxf(smx[2], smx[3]));
    ssc[0] = fmaxf((mx - mn) / 254.0f, 1e-8f);
    if (qb == 0) scl[0] = ssc[0];
  }
  __syncthreads();
  const float s = ssc[0];
  int i = qb * 256 + t;
  float4 v = ((const float4*)x)[i];
  float a = fminf(fmaxf(rintf(v.x / s), -127.f), 127.f);
  float b = fminf(fmaxf(rintf(v.y / s), -127.f), 127.f);
  float c = fminf(fmaxf(rintf(v.z / s), -127.f), 127.f);
  float d = fminf(fmaxf(rintf(v.w / s), -127.f), 127.f);
  ((ushort4*)xq)[i] = make_ushort4(f2bf(a), f2bf(b), f2bf(c), f2bf(d));
  // Sx[b][k] = sum_n Xi (unscaled)
  float s4 = a + b + c + d;
  s4 += __shfl_down(s4, 16);
  s4 += __shfl_down(s4, 8);
  s4 += __shfl_down(s4, 4);
  s4 += __shfl_down(s4, 2);
  s4 += __shfl_down(s4, 1);
  if ((t & 31) == 0) {
    int bb = qb >> 2, kk = ((qb & 3) << 3) + (t >> 5);
    Sx[bb * 32 + kk] = s4;
  }
}

// ---------------- 3) mega: fused chained einsum; 256 blocks (j=bid>>3, btile=bid&7) ----------------
__global__ __launch_bounds__(256, 1) void k_mega(const unsigned short* __restrict__ Xq,
                                                 const float* __restrict__ Sx,
                                                 const float* __restrict__ Ysg,
                                                 const float* __restrict__ Zsg,
                                                 const float* __restrict__ Ysc,
                                                 const float* __restrict__ Zsc,
                                                 const float* __restrict__ Acoef,
                                                 const float* __restrict__ scl,
                                                 const float* __restrict__ bias,
                                                 float* __restrict__ out) {
  __shared__ __align__(16) unsigned short Xb[2][64 * 128];  // [row b][256B], XOR swz, 2x16KB
  __shared__ __align__(16) unsigned short Zb[32 * 128];     // [p*16+l][256B], XOR swz, 8KB
  __shared__ __align__(16) unsigned short Yeb[128 * 40];    // [m][40 halves], pl in [0,32)
  __shared__ __align__(16) unsigned short Tl[4 * 16 * 40];  // per-wave [b16][40]
  __shared__ float eb[128];
  __shared__ float Sxb[64 * 32];
  __shared__ float cfs[32][8];  // per k: c0[2], cf2[2], az[2], Dv
  const int t = threadIdx.x, lane = t & 63, wid = t >> 6;
  const int btile = blockIdx.x & 7;  // bid%8 -> XCD-local X sharing
  const int j = blockIdx.x >> 3;

  // ---- prologue staging ----
#pragma unroll
  for (int rep = 0; rep < 2; ++rep) {
    int i4 = t + rep * 256;  // 512 float4 = 2048 f32
    ((float4*)Sxb)[i4] = ((const float4*)(Sx + btile * 2048))[i4];
  }
  if (t < 64) {
    int k = t & 31, p = t >> 5;
    int idx = p * 1024 + j * 32 + k;
    float ys = Ysc[idx], zs = Zsc[idx];
    const float* Ap = Acoef + (size_t)idx * 4;
    cfs[k][p] = Ap[0] * ys * zs;
    cfs[k][2 + p] = Ap[1] * ys;
    cfs[k][4 + p] = Ap[2] * zs;
    if (p == 0)
      cfs[k][6] = Acoef[(size_t)(j * 32 + k) * 4 + 3] + Acoef[(size_t)(1024 + j * 32 + k) * 4 + 3];
  }
  // prefetch regs for k=0
  float4 zr[2][4], yr[2][4];
#pragma unroll
  for (int rep = 0; rep < 4; ++rep) {
    int q4 = rep * 256 + t;
    {
      int n0 = (q4 & 31) * 4, l = (q4 >> 5) & 15, p = q4 >> 9;
      zr[0][rep] = *(const float4*)(Zsg + (size_t)(p * 1024 + j * 32) * 2048 + l * 128 + n0);
    }
    {
      int l0 = (q4 & 3) * 4, m = (q4 >> 2) & 127, p = q4 >> 9;
      yr[0][rep] = *(const float4*)(Ysg + (size_t)(p * 1024 + j * 32) * 2048 + m * 16 + l0);
    }
  }
  // gload X(0) -> Xb[0]
#pragma unroll
  for (int c = 0; c < 4; ++c) {
    int chunk = wid * 4 + c;
    int row = chunk * 4 + (lane >> 4);
    int colb = ((lane & 15) * 16) ^ ((row & 7) << 4);
    load_lds16(Xq + (size_t)(btile * 64 + row) * 4096 + (colb >> 1),
               (unsigned short*)Xb[0] + chunk * 512);
  }
  f32x4 acc[8];
#pragma unroll
  for (int mt = 0; mt < 8; ++mt) acc[mt] = (f32x4)(0.f);
  __syncthreads();  // Sxb/cfs visible; drains prologue loads (harmless)

#pragma unroll 2
  for (int k = 0; k < 32; ++k) {
    const int cur = k & 1, nxt = cur ^ 1;
    const float c00 = cfs[k][0], c01 = cfs[k][1];
    const float cf20 = cfs[k][2], cf21 = cfs[k][3];
    const float az0 = cfs[k][4], az1 = cfs[k][5];
    const float Dv = cfs[k][6];
    // ---- Phase A: cvt + LDS stage (Zb, Yeb, eb) ----
#pragma unroll
    for (int rep = 0; rep < 4; ++rep) {
      int q4 = rep * 256 + t;
      int n0 = (q4 & 31) * 4, l = (q4 >> 5) & 15, p = q4 >> 9;
      float4 v = zr[cur][rep];
      ushort4 o = make_ushort4(f2bf(v.x), f2bf(v.y), f2bf(v.z), f2bf(v.w));
      *(ushort4*)&Zb[(p * 16 + l) * 128 + (n0 ^ ((l & 7) << 3))] = o;
    }
    float ereg0 = 0.f, ereg1 = 0.f;
#pragma unroll
    for (int rep = 0; rep < 4; ++rep) {
      int q4 = rep * 256 + t;
      int l0 = (q4 & 3) * 4, m = (q4 >> 2) & 127, p = q4 >> 9;
      float4 v = yr[cur][rep];
      float s4 = v.x + v.y + v.z + v.w;
      s4 += __shfl_xor(s4, 1);
      s4 += __shfl_xor(s4, 2);
      float cf2 = p ? cf21 : cf20;
      if ((rep & 1) == 0) ereg0 += cf2 * s4; else ereg1 += cf2 * s4;
      float c0 = p ? c01 : c00;
      float az = p ? az1 : az0;
      ushort4 o = make_ushort4(f2bf(c0 * v.x + az), f2bf(c0 * v.y + az),
                               f2bf(c0 * v.z + az), f2bf(c0 * v.w + az));
      *(ushort4*)&Yeb[m * 40 + p * 16 + l0] = o;
    }
    if ((t & 3) == 0) {
      int ma = t >> 2;  // 0..63
      eb[ma] = ereg0 + Dv;
      eb[64 + ma] = ereg1 + Dv;
    }
    // ---- Phase B: prefetch k+1, counted wait, barrier ----
    if (k < 31) {
#pragma unroll
      for (int c = 0; c < 4; ++c) {
        int chunk = wid * 4 + c;
        int row = chunk * 4 + (lane >> 4);
        int colb = ((lane & 15) * 16) ^ ((row & 7) << 4);
        load_lds16(Xq + (size_t)(btile * 64 + row) * 4096 + (k + 1) * 128 + (colb >> 1),
                   (unsigned short*)Xb[nxt] + chunk * 512);
      }
#pragma unroll
      for (int rep = 0; rep < 4; ++rep) {
        int q4 = rep * 256 + t;
        {
          int n0 = (q4 & 31) * 4, l = (q4 >> 5) & 15, p = q4 >> 9;
          zr[nxt][rep] = *(const float4*)(Zsg + (size_t)(p * 1024 + j * 32 + k + 1) * 2048 + l * 128 + n0);
        }
        {
          int l0 = (q4 & 3) * 4, m = (q4 >> 2) & 127, p = q4 >> 9;
          yr[nxt][rep] = *(const float4*)(Ysg + (size_t)(p * 1024 + j * 32 + k + 1) * 2048 + m * 16 + l0);
        }
      }
      __builtin_amdgcn_sched_barrier(0);
      asm volatile("s_waitcnt vmcnt(12) lgkmcnt(0)" ::: "memory");  // X(k) landed; 12 in flight
      __builtin_amdgcn_sched_barrier(0);
    } else {
      __builtin_amdgcn_sched_barrier(0);
      asm volatile("s_waitcnt vmcnt(0) lgkmcnt(0)" ::: "memory");
      __builtin_amdgcn_sched_barrier(0);
    }
    __builtin_amdgcn_s_barrier();
    __builtin_amdgcn_sched_barrier(0);
    // ---- Phase C: T-mfma  T[b,l] = sum_n Xi[b,n]*Z[l,n] ----
    const char* xbase = (const char*)Xb[cur];
    const int arow = wid * 16 + (lane & 15);
    bf16x8 afr[4];
#pragma unroll
    for (int c = 0; c < 4; ++c)
      afr[c] = *(const bf16x8*)(xbase + arow * 256 +
                                (((c * 64 + ((lane >> 4) * 16))) ^ ((arow & 7) << 4)));
    f32x4 t0 = (f32x4)(0.f), t1 = (f32x4)(0.f);
    const int zr0 = (lane & 15), zr1 = 16 + (lane & 15);
#pragma unroll
    for (int c = 0; c < 4; ++c) {
      bf16x8 z0 = *(const bf16x8*)((const char*)Zb + zr0 * 256 +
                                   ((c * 64 + ((lane >> 4) * 16)) ^ ((zr0 & 7) << 4)));
      bf16x8 z1 = *(const bf16x8*)((const char*)Zb + zr1 * 256 +
                                   ((c * 64 + ((lane >> 4) * 16)) ^ ((zr1 & 7) << 4)));
      t0 = __builtin_amdgcn_mfma_f32_16x16x32_bf16(afr[c], z0, t0, 0, 0, 0);
      t1 = __builtin_amdgcn_mfma_f32_16x16x32_bf16(afr[c], z1, t1, 0, 0, 0);
    }
    // ---- Phase D: T transpose via per-wave LDS + rank-1 (Sx*e) ----
    unsigned short* tl = Tl + wid * 640;
#pragma unroll
    for (int i = 0; i < 4; ++i) {
      int r = (lane >> 4) * 4 + i;
      tl[r * 40 + (lane & 15)] = f2bf(t0[i]);
      tl[r * 40 + 16 + (lane & 15)] = f2bf(t1[i]);
    }
#pragma unroll
    for (int i = 0; i < 4; ++i) {
      float sx = Sxb[(wid * 16 + (lane >> 4) * 4 + i) * 32 + k];
#pragma unroll
      for (int mt = 0; mt < 8; ++mt) acc[mt][i] += sx * eb[mt * 16 + (lane & 15)];
    }
    // ---- Phase E: core  acc[b,m] += sum_pl T[b,pl]*Ye[m,pl] ----
    bf16x8 tf = *(const bf16x8*)((const char*)Tl + wid * 1280 + (lane & 15) * 80 +
                                 ((lane >> 4) * 16));
#pragma unroll
    for (int mt = 0; mt < 8; ++mt) {
      bf16x8 yf = *(const bf16x8*)((const char*)Yeb + (mt * 16 + (lane & 15)) * 80 +
                                   ((lane >> 4) * 16));
      acc[mt] = __builtin_amdgcn_mfma_f32_16x16x32_bf16(tf, yf, acc[mt], 0, 0, 0);
    }
    __builtin_amdgcn_sched_barrier(0);
    __builtin_amdgcn_s_barrier();  // reads done before next-iter staging overwrites
    __builtin_amdgcn_sched_barrier(0);
  }

  // ---- epilogue: out = acc*s + bias ----
  const float s = scl[0];
#pragma unroll
  for (int mt = 0; mt < 8; ++mt) {
    int col = j * 128 + mt * 16 + (lane & 15);
    float bv = bias[col];
#pragma unroll
    for (int i = 0; i < 4; ++i) {
      int b = btile * 64 + wid * 16 + (lane >> 4) * 4 + i;
      out[(size_t)b * 4096 + col] = acc[mt][i] * s + bv;
    }
  }
}

extern "C" void kernel_launch(void* const* d_in, const int* in_sizes, int n_in,
                              void* d_out, int out_size, void* d_ws, size_t ws_size,
                              hipStream_t stream) {
  const float* x    = (const float*)d_in[0];  // (1,512,4096)
  const float* Ysg  = (const float*)d_in[1];  // (2,32,32,128,16)
  const float* Zsg  = (const float*)d_in[2];  // (2,32,32,16,128)
  const float* Ysc  = (const float*)d_in[3];  // (2,32,32)
  const float* Zsc  = (const float*)d_in[4];  // (2,32,32)
  const float* A    = (const float*)d_in[5];  // (2,32,32,4)
  const float* bias = (const float*)d_in[6];  // (4096,)
  float* out = (float*)d_out;

  char* ws = (char*)d_ws;
  float* scl  = (float*)ws;                        // [0] act_scale
  float* part = (float*)(ws + 256);                // 512 f32
  float* Sx   = (float*)(ws + 8192);               // 512x32 f32 = 64KB
  unsigned short* Xq = (unsigned short*)(ws + 131072);  // 4MB bf16

  k_minmax_part<<<dim3(256), dim3(256), 0, stream>>>(x, part);
  k_quant<<<dim3(2048), dim3(256), 0, stream>>>(x, part, scl, Xq, Sx);
  k_mega<<<dim3(256), dim3(256), 0, stream>>>(Xq, Sx, Ysg, Zsg, Ysc, Zsc, A, scl, bias, out);
}

// Round 10
// 72.920 us; speedup vs baseline: 1.0114x; 1.0114x over previous
//
#include <hip/hip_runtime.h>
#include <hip/hip_bf16.h>

// BQQ dims: P=2, J=32, K=32, M=128, L=16, N=128; B=512
// No-W dataflow:
//   out[b, j*128+m] = s * ( sum_k [ sum_pl Ye[m,pl]*T[b,pl] + Sx[b,k]*e[m] ] ) + bias
//   T[b,l](p,j,k) = sum_n Xi[b,kn]*Zsign[l,n]   (MFMA, exact ints in f32)
//   Ye[m,pl] = c0_p*Ysign[m,l] + az_p           (az=A2*Zsc folds out3)
//   e[m]     = sum_p (A1*Ysc)*Ysum[p,m] + sum_p A3  (folds out2+out4)
typedef __attribute__((ext_vector_type(4))) float f32x4;
typedef __attribute__((ext_vector_type(8))) short bf16x8;

#define GLOBAL_AS __attribute__((address_space(1)))
#define LDS_AS __attribute__((address_space(3)))

static __device__ __forceinline__ unsigned short f2bf(float f) {
  __hip_bfloat16 h = __float2bfloat16(f);
  return __builtin_bit_cast(unsigned short, h);
}
static __device__ __forceinline__ void load_lds16(const void* g, void* l) {
  __builtin_amdgcn_global_load_lds((GLOBAL_AS void*)g, (LDS_AS void*)l, 16, 0, 0);
}

// ---------------- 1) per-block min/max of input (2M f32), 256 blocks ----------------
__global__ __launch_bounds__(256) void k_minmax_part(const float* __restrict__ x,
                                                     float* __restrict__ part) {
  int tid = blockIdx.x * 256 + threadIdx.x;
  const float4* xv = (const float4*)x;
  float mn = 3.4e38f, mx = -3.4e38f;
#pragma unroll
  for (int rep = 0; rep < 8; ++rep) {
    float4 v = xv[tid + rep * 65536];
    mn = fminf(mn, fminf(fminf(v.x, v.y), fminf(v.z, v.w)));
    mx = fmaxf(mx, fmaxf(fmaxf(v.x, v.y), fmaxf(v.z, v.w)));
  }
#pragma unroll
  for (int o = 32; o > 0; o >>= 1) {
    mn = fminf(mn, __shfl_down(mn, o));
    mx = fmaxf(mx, __shfl_down(mx, o));
  }
  __shared__ float smn[4], smx[4];
  int lane = threadIdx.x & 63, w = threadIdx.x >> 6;
  if (lane == 0) { smn[w] = mn; smx[w] = mx; }
  __syncthreads();
  if (threadIdx.x == 0) {
    mn = fminf(fminf(smn[0], smn[1]), fminf(smn[2], smn[3]));
    mx = fmaxf(fmaxf(smx[0], smx[1]), fmaxf(smx[2], smx[3]));
    part[2 * blockIdx.x] = mn;
    part[2 * blockIdx.x + 1] = mx;
  }
}

// ---------------- 2) quantize + Sx row-sums; 2048 blocks ----------------
__global__ __launch_bounds__(256) void k_quant(const float* __restrict__ x,
                                               const float* __restrict__ part,
                                               float* __restrict__ scl,
                                               unsigned short* __restrict__ xq,
                                               float* __restrict__ Sx) {
  const int t = threadIdx.x, qb = blockIdx.x;
  float2 v2 = ((const float2*)part)[t];
  float mn = v2.x, mx = v2.y;
#pragma unroll
  for (int o = 32; o > 0; o >>= 1) {
    mn = fminf(mn, __shfl_down(mn, o));
    mx = fmaxf(mx, __shfl_down(mx, o));
  }
  __shared__ float smn[4], smx[4], ssc[1];
  int lane = t & 63, w = t >> 6;
  if (lane == 0) { smn[w] = mn; smx[w] = mx; }
  __syncthreads();
  if (t == 0) {
    mn = fminf(fminf(smn[0], smn[1]), fminf(smn[2], smn[3]));
    mx = fmaxf(fmaxf(smx[0], smx[1]), fmaxf(smx[2], smx[3]));
    ssc[0] = fmaxf((mx - mn) / 254.0f, 1e-8f);
    if (qb == 0) scl[0] = ssc[0];
  }
  __syncthreads();
  const float s = ssc[0];
  int i = qb * 256 + t;
  float4 v = ((const float4*)x)[i];
  float a = fminf(fmaxf(rintf(v.x / s), -127.f), 127.f);
  float b = fminf(fmaxf(rintf(v.y / s), -127.f), 127.f);
  float c = fminf(fmaxf(rintf(v.z / s), -127.f), 127.f);
  float d = fminf(fmaxf(rintf(v.w / s), -127.f), 127.f);
  ((ushort4*)xq)[i] = make_ushort4(f2bf(a), f2bf(b), f2bf(c), f2bf(d));
  float s4 = a + b + c + d;
  s4 += __shfl_down(s4, 16);
  s4 += __shfl_down(s4, 8);
  s4 += __shfl_down(s4, 4);
  s4 += __shfl_down(s4, 2);
  s4 += __shfl_down(s4, 1);
  if ((t & 31) == 0) {
    int bb = qb >> 2, kk = ((qb & 3) << 3) + (t >> 5);
    Sx[bb * 32 + kk] = s4;
  }
}

// ---------------- 3) mega: grid 512 (2 blocks/CU), XCD-local j ----------------
// xcd = bid&7; j = xcd*4 + ((bid>>3)&3)  -> each XCD touches 4 js = 4MB signs = its L2.
// btile = bid>>5 (16 tiles x 32 b-rows). 4 waves: bhalf=wid&1 (16 b-rows), mhalf=wid>>1
// (64 m-cols). Each wave computes its own T (redundant across m-split, 8 T-mfma) then
// 4 core-mfma. X double-buffered via gload_lds + counted vmcnt(2); Z/Y loaded direct
// (L2-local by construction; latency hidden by the co-resident sibling block).
__global__ __launch_bounds__(256, 2) void k_mega(const unsigned short* __restrict__ Xq,
                                                 const float* __restrict__ Sx,
                                                 const float* __restrict__ Ysg,
                                                 const float* __restrict__ Zsg,
                                                 const float* __restrict__ Ysc,
                                                 const float* __restrict__ Zsc,
                                                 const float* __restrict__ Acoef,
                                                 const float* __restrict__ scl,
                                                 const float* __restrict__ bias,
                                                 float* __restrict__ out) {
  __shared__ __align__(16) unsigned short Xb[2][32 * 128];  // 2 x 8KB, XOR swz
  __shared__ __align__(16) unsigned short Zb[32 * 128];     // [p*16+l][256B], XOR swz, 8KB
  __shared__ __align__(16) unsigned short Yeb[128 * 40];    // [m][40 halves], pl in [0,32)
  __shared__ __align__(16) unsigned short Tl[4 * 16 * 40];  // per-wave [b16][40]
  __shared__ float eb[128];
  __shared__ float Sxb[32 * 33];  // pitch 33: conflict-free rank-1 reads
  __shared__ float cfs[32][8];
  const int t = threadIdx.x, lane = t & 63, wid = t >> 6;
  const int bid = blockIdx.x;
  const int j = (bid & 7) * 4 + ((bid >> 3) & 3);  // XCD-local j group
  const int btile = bid >> 5;                      // 0..15, 32 b-rows each
  const int bhalf = wid & 1, mhalf = wid >> 1;

  // ---- prologue staging ----
#pragma unroll
  for (int rep = 0; rep < 4; ++rep) {
    int idx = rep * 256 + t;  // 1024 f32
    Sxb[(idx >> 5) * 33 + (idx & 31)] = Sx[btile * 1024 + idx];
  }
  if (t < 64) {
    int k = t & 31, p = t >> 5;
    int idx = p * 1024 + j * 32 + k;
    float ys = Ysc[idx], zs = Zsc[idx];
    const float* Ap = Acoef + (size_t)idx * 4;
    cfs[k][p] = Ap[0] * ys * zs;
    cfs[k][2 + p] = Ap[1] * ys;
    cfs[k][4 + p] = Ap[2] * zs;
    if (p == 0)
      cfs[k][6] = Acoef[(size_t)(j * 32 + k) * 4 + 3] + Acoef[(size_t)(1024 + j * 32 + k) * 4 + 3];
  }
  // gload X(0) -> Xb[0]: 8 chunks of 1KB, 2 per wave
#pragma unroll
  for (int c = 0; c < 2; ++c) {
    int chunk = wid * 2 + c;
    int row = chunk * 4 + (lane >> 4);
    int colb = ((lane & 15) * 16) ^ ((row & 7) << 4);
    load_lds16(Xq + (size_t)(btile * 32 + row) * 4096 + (colb >> 1),
               (unsigned short*)Xb[0] + chunk * 512);
  }
  f32x4 acc[4];
#pragma unroll
  for (int mi = 0; mi < 4; ++mi) acc[mi] = (f32x4)(0.f);
  __syncthreads();  // Sxb/cfs visible

#pragma unroll 2
  for (int k = 0; k < 32; ++k) {
    const int cur = k & 1, nxt = cur ^ 1;
    const float c00 = cfs[k][0], c01 = cfs[k][1];
    const float cf20 = cfs[k][2], cf21 = cfs[k][3];
    const float az0 = cfs[k][4], az1 = cfs[k][5];
    const float Dv = cfs[k][6];
    // ---- Phase A: direct loads (L2-local) + cvt + LDS stage ----
#pragma unroll
    for (int rep = 0; rep < 4; ++rep) {
      int q4 = rep * 256 + t;
      int n0 = (q4 & 31) * 4, l = (q4 >> 5) & 15, p = q4 >> 9;
      float4 v = *(const float4*)(Zsg + (size_t)(p * 1024 + j * 32 + k) * 2048 + l * 128 + n0);
      ushort4 o = make_ushort4(f2bf(v.x), f2bf(v.y), f2bf(v.z), f2bf(v.w));
      *(ushort4*)&Zb[(p * 16 + l) * 128 + (n0 ^ ((l & 7) << 3))] = o;
    }
    float ereg0 = 0.f, ereg1 = 0.f;
#pragma unroll
    for (int rep = 0; rep < 4; ++rep) {
      int q4 = rep * 256 + t;
      int l0 = (q4 & 3) * 4, m = (q4 >> 2) & 127, p = q4 >> 9;
      float4 v = *(const float4*)(Ysg + (size_t)(p * 1024 + j * 32 + k) * 2048 + m * 16 + l0);
      float s4 = v.x + v.y + v.z + v.w;
      s4 += __shfl_xor(s4, 1);
      s4 += __shfl_xor(s4, 2);
      float cf2 = p ? cf21 : cf20;
      if ((rep & 1) == 0) ereg0 += cf2 * s4; else ereg1 += cf2 * s4;
      float c0 = p ? c01 : c00;
      float az = p ? az1 : az0;
      ushort4 o = make_ushort4(f2bf(c0 * v.x + az), f2bf(c0 * v.y + az),
                               f2bf(c0 * v.z + az), f2bf(c0 * v.w + az));
      *(ushort4*)&Yeb[m * 40 + p * 16 + l0] = o;
    }
    if ((t & 3) == 0) {
      int ma = t >> 2;
      eb[ma] = ereg0 + Dv;
      eb[64 + ma] = ereg1 + Dv;
    }
    // ---- Phase B: prefetch X(k+1), counted wait, barrier ----
    if (k < 31) {
#pragma unroll
      for (int c = 0; c < 2; ++c) {
        int chunk = wid * 2 + c;
        int row = chunk * 4 + (lane >> 4);
        int colb = ((lane & 15) * 16) ^ ((row & 7) << 4);
        load_lds16(Xq + (size_t)(btile * 32 + row) * 4096 + (k + 1) * 128 + (colb >> 1),
                   (unsigned short*)Xb[nxt] + chunk * 512);
      }
      __builtin_amdgcn_sched_barrier(0);
      asm volatile("s_waitcnt vmcnt(2) lgkmcnt(0)" ::: "memory");  // X(k) landed
      __builtin_amdgcn_sched_barrier(0);
    } else {
      __builtin_amdgcn_sched_barrier(0);
      asm volatile("s_waitcnt vmcnt(0) lgkmcnt(0)" ::: "memory");
      __builtin_amdgcn_sched_barrier(0);
    }
    __builtin_amdgcn_s_barrier();
    __builtin_amdgcn_sched_barrier(0);
    // ---- Phase C: T-mfma  T[b,l] = sum_n Xi[b,n]*Z[l,n] ----
    const char* xbase = (const char*)Xb[cur];
    const int arow = bhalf * 16 + (lane & 15);
    bf16x8 afr[4];
#pragma unroll
    for (int c = 0; c < 4; ++c)
      afr[c] = *(const bf16x8*)(xbase + arow * 256 +
                                ((c * 64 + ((lane >> 4) * 16)) ^ ((arow & 7) << 4)));
    f32x4 t0 = (f32x4)(0.f), t1 = (f32x4)(0.f);
    const int zr0 = (lane & 15), zr1 = 16 + (lane & 15);
#pragma unroll
    for (int c = 0; c < 4; ++c) {
      bf16x8 z0 = *(const bf16x8*)((const char*)Zb + zr0 * 256 +
                                   ((c * 64 + ((lane >> 4) * 16)) ^ ((zr0 & 7) << 4)));
      bf16x8 z1 = *(const bf16x8*)((const char*)Zb + zr1 * 256 +
                                   ((c * 64 + ((lane >> 4) * 16)) ^ ((zr1 & 7) << 4)));
      t0 = __builtin_amdgcn_mfma_f32_16x16x32_bf16(afr[c], z0, t0, 0, 0, 0);
      t1 = __builtin_amdgcn_mfma_f32_16x16x32_bf16(afr[c], z1, t1, 0, 0, 0);
    }
    // ---- Phase D: transpose T via per-wave LDS + rank-1 (Sx*e) ----
    unsigned short* tl = Tl + wid * 640;
#pragma unroll
    for (int i = 0; i < 4; ++i) {
      int r = (lane >> 4) * 4 + i;
      tl[r * 40 + (lane & 15)] = f2bf(t0[i]);
      tl[r * 40 + 16 + (lane & 15)] = f2bf(t1[i]);
    }
#pragma unroll
    for (int i = 0; i < 4; ++i) {
      float sx = Sxb[(bhalf * 16 + (lane >> 4) * 4 + i) * 33 + k];
#pragma unroll
      for (int mi = 0; mi < 4; ++mi)
        acc[mi][i] += sx * eb[mhalf * 64 + mi * 16 + (lane & 15)];
    }
    // ---- Phase E: core  acc[b,m] += sum_pl T[b,pl]*Ye[m,pl] ----
    bf16x8 tf = *(const bf16x8*)((const char*)Tl + wid * 1280 + (lane & 15) * 80 +
                                 ((lane >> 4) * 16));
#pragma unroll
    for (int mi = 0; mi < 4; ++mi) {
      bf16x8 yf = *(const bf16x8*)((const char*)Yeb + (mhalf * 64 + mi * 16 + (lane & 15)) * 80 +
                                   ((lane >> 4) * 16));
      acc[mi] = __builtin_amdgcn_mfma_f32_16x16x32_bf16(tf, yf, acc[mi], 0, 0, 0);
    }
    __builtin_amdgcn_sched_barrier(0);
    __builtin_amdgcn_s_barrier();  // all reads done before next-iter staging
    __builtin_amdgcn_sched_barrier(0);
  }

  // ---- epilogue: out = acc*s + bias ----
  const float s = scl[0];
#pragma unroll
  for (int mi = 0; mi < 4; ++mi) {
    int col = j * 128 + (mhalf * 4 + mi) * 16 + (lane & 15);
    float bv = bias[col];
#pragma unroll
    for (int i = 0; i < 4; ++i) {
      int b = btile * 32 + bhalf * 16 + (lane >> 4) * 4 + i;
      out[(size_t)b * 4096 + col] = acc[mi][i] * s + bv;
    }
  }
}

extern "C" void kernel_launch(void* const* d_in, const int* in_sizes, int n_in,
                              void* d_out, int out_size, void* d_ws, size_t ws_size,
                              hipStream_t stream) {
  const float* x    = (const float*)d_in[0];  // (1,512,4096)
  const float* Ysg  = (const float*)d_in[1];  // (2,32,32,128,16)
  const float* Zsg  = (const float*)d_in[2];  // (2,32,32,16,128)
  const float* Ysc  = (const float*)d_in[3];  // (2,32,32)
  const float* Zsc  = (const float*)d_in[4];  // (2,32,32)
  const float* A    = (const float*)d_in[5];  // (2,32,32,4)
  const float* bias = (const float*)d_in[6];  // (4096,)
  float* out = (float*)d_out;

  char* ws = (char*)d_ws;
  float* scl  = (float*)ws;                        // [0] act_scale
  float* part = (float*)(ws + 256);                // 512 f32
  float* Sx   = (float*)(ws + 8192);               // 512x32 f32 = 64KB
  unsigned short* Xq = (unsigned short*)(ws + 131072);  // 4MB bf16

  k_minmax_part<<<dim3(256), dim3(256), 0, stream>>>(x, part);
  k_quant<<<dim3(2048), dim3(256), 0, stream>>>(x, part, scl, Xq, Sx);
  k_mega<<<dim3(512), dim3(256), 0, stream>>>(Xq, Sx, Ysg, Zsg, Ysc, Zsc, A, scl, bias, out);
}

// Round 11
// 55.551 us; speedup vs baseline: 1.3277x; 1.3127x over previous
//
#include <hip/hip_runtime.h>
#include <hip/hip_bf16.h>

// BQQ dims: P=2, J=32, K=32, M=128, L=16, N=128; B=512; in=kn=4096; out=jm=4096
typedef __attribute__((ext_vector_type(4))) float f32x4;
typedef __attribute__((ext_vector_type(8))) short bf16x8;
typedef __attribute__((ext_vector_type(4))) unsigned int u32x4;

#define GLOBAL_AS __attribute__((address_space(1)))
#define LDS_AS __attribute__((address_space(3)))

static __device__ __forceinline__ unsigned short f2bf(float f) {
  __hip_bfloat16 h = __float2bfloat16(f);
  return __builtin_bit_cast(unsigned short, h);
}
static __device__ __forceinline__ float bf2f(unsigned short u) {
  unsigned int v = ((unsigned int)u) << 16;
  return __builtin_bit_cast(float, v);
}
static __device__ __forceinline__ void load_lds16(const void* g, void* l) {
  __builtin_amdgcn_global_load_lds((GLOBAL_AS void*)g, (LDS_AS void*)l, 16, 0, 0);
}

// ---------------- 1) per-block min/max of input (2M f32), 256 blocks ----------------
__global__ __launch_bounds__(256) void k_minmax_part(const float* __restrict__ x,
                                                     float* __restrict__ part) {
  int tid = blockIdx.x * 256 + threadIdx.x;
  const float4* xv = (const float4*)x;
  float mn = 3.4e38f, mx = -3.4e38f;
#pragma unroll
  for (int rep = 0; rep < 8; ++rep) {
    float4 v = xv[tid + rep * 65536];
    mn = fminf(mn, fminf(fminf(v.x, v.y), fminf(v.z, v.w)));
    mx = fmaxf(mx, fmaxf(fmaxf(v.x, v.y), fmaxf(v.z, v.w)));
  }
#pragma unroll
  for (int o = 32; o > 0; o >>= 1) {
    mn = fminf(mn, __shfl_down(mn, o));
    mx = fmaxf(mx, __shfl_down(mx, o));
  }
  __shared__ float smn[4], smx[4];
  int lane = threadIdx.x & 63, w = threadIdx.x >> 6;
  if (lane == 0) { smn[w] = mn; smx[w] = mx; }
  __syncthreads();
  if (threadIdx.x == 0) {
    mn = fminf(fminf(smn[0], smn[1]), fminf(smn[2], smn[3]));
    mx = fmaxf(fmaxf(smx[0], smx[1]), fmaxf(smx[2], smx[3]));
    part[2 * blockIdx.x] = mn;
    part[2 * blockIdx.x + 1] = mx;
  }
}

// ---------------- 2) fused: blocks 0..1023 = build W (MFMA); 1024..3071 = quantize ----------------
__global__ __launch_bounds__(256) void k_fused(const float* __restrict__ x,
                                               const float* __restrict__ part,
                                               const float* __restrict__ Ysg,
                                               const float* __restrict__ Zsg,
                                               const float* __restrict__ Ysc,
                                               const float* __restrict__ Zsc,
                                               const float* __restrict__ Acoef,
                                               float* __restrict__ scl,
                                               unsigned short* __restrict__ xq,
                                               unsigned short* __restrict__ W) {
  const int t = threadIdx.x;
  if (blockIdx.x < 1024) {
    // ---- build_w (MFMA) ----
    const int jk = blockIdx.x;  // j*32+k
    __shared__ unsigned short Yb[2 * 128 * 24];  // [p*128+m][24] halves; data in [0..16)
    __shared__ unsigned short Zb[128 * 36];      // [n][36] halves; data pl in [0..32)
    __shared__ float B1p[2][128];
    __shared__ float C1[128];
    float cf0[2], cf2[2], cf4[2];
    float Dv;
    {
      float ys0 = Ysc[jk], zs0 = Zsc[jk], ys1 = Ysc[1024 + jk], zs1 = Zsc[1024 + jk];
      const float* A0p = Acoef + (size_t)jk * 4;
      const float* A1p = Acoef + (size_t)(1024 + jk) * 4;
      cf0[0] = A0p[0] * ys0 * zs0; cf0[1] = A1p[0] * ys1 * zs1;
      cf2[0] = A0p[1] * ys0;       cf2[1] = A1p[1] * ys1;
      cf4[0] = A0p[2] * zs0;       cf4[1] = A1p[2] * zs1;
      Dv = A0p[3] + A1p[3];
    }
#pragma unroll
    for (int rep = 0; rep < 4; ++rep) {
      int q = rep * 256 + t;
      int l0 = (q & 3) * 4, m = (q >> 2) & 127, p = q >> 9;
      float4 v = *(const float4*)(Ysg + (size_t)(p * 1024 + jk) * 2048 + m * 16 + l0);
      float s4 = v.x + v.y + v.z + v.w;
      s4 += __shfl_xor(s4, 1);
      s4 += __shfl_xor(s4, 2);
      if ((t & 3) == 0) B1p[p][m] = s4;
      float c0 = cf0[p];
      ushort4 o = make_ushort4(f2bf(c0 * v.x), f2bf(c0 * v.y), f2bf(c0 * v.z), f2bf(c0 * v.w));
      *(ushort4*)&Yb[(p * 128 + m) * 24 + l0] = o;
    }
#pragma unroll
    for (int rep = 0; rep < 4; ++rep) {
      int q = rep * 256 + t;
      int n0 = (q & 31) * 4, l = (q >> 5) & 15, p = q >> 9;
      float4 v = *(const float4*)(Zsg + (size_t)(p * 1024 + jk) * 2048 + l * 128 + n0);
      int pl = p * 16 + l;
      Zb[(n0 + 0) * 36 + pl] = f2bf(v.x);
      Zb[(n0 + 1) * 36 + pl] = f2bf(v.y);
      Zb[(n0 + 2) * 36 + pl] = f2bf(v.z);
      Zb[(n0 + 3) * 36 + pl] = f2bf(v.w);
    }
    __syncthreads();
    if (t < 128) {
      float s0 = 0.f, s1 = 0.f;
#pragma unroll
      for (int l = 0; l < 16; ++l) {
        s0 += bf2f(Zb[t * 36 + l]);
        s1 += bf2f(Zb[t * 36 + 16 + l]);
      }
      C1[t] = cf4[0] * s0 + cf4[1] * s1;
    }
    __syncthreads();
    const int lane = t & 63, wid = t >> 6;
    const int wm = wid >> 1, wn = wid & 1;
    const int grp = lane >> 4;
    bf16x8 af[4], bfr[4];
#pragma unroll
    for (int fm = 0; fm < 4; ++fm) {
      int m = wm * 64 + fm * 16 + (lane & 15);
      af[fm] = *(const bf16x8*)((const char*)Yb + ((grp >> 1) * 128 + m) * 48 + (grp & 1) * 16);
    }
#pragma unroll
    for (int fn = 0; fn < 4; ++fn) {
      int n = wn * 64 + fn * 16 + (lane & 15);
      const char* zp = (const char*)Zb + n * 72 + grp * 16;
      uint2 z0 = *(const uint2*)zp;
      uint2 z1 = *(const uint2*)(zp + 8);
      u32x4 zw; zw[0] = z0.x; zw[1] = z0.y; zw[2] = z1.x; zw[3] = z1.y;
      bfr[fn] = __builtin_bit_cast(bf16x8, zw);
    }
    f32x4 acc[4][4];
#pragma unroll
    for (int fm = 0; fm < 4; ++fm)
#pragma unroll
      for (int fn = 0; fn < 4; ++fn)
        acc[fm][fn] = __builtin_amdgcn_mfma_f32_16x16x32_bf16(af[fm], bfr[fn], (f32x4)(0.f), 0, 0, 0);
    const int j = jk >> 5, k = jk & 31;
    float c1v[4];
#pragma unroll
    for (int fn = 0; fn < 4; ++fn) c1v[fn] = C1[wn * 64 + fn * 16 + (lane & 15)];
#pragma unroll
    for (int fm = 0; fm < 4; ++fm) {
#pragma unroll
      for (int i = 0; i < 4; ++i) {
        int row = wm * 64 + fm * 16 + (grp)*4 + i;
        float b1v = cf2[0] * B1p[0][row] + cf2[1] * B1p[1][row] + Dv;
        size_t rowoff = (size_t)(j * 128 + row) * 4096 + (size_t)(k * 128);
#pragma unroll
        for (int fn = 0; fn < 4; ++fn) {
          int col = wn * 64 + fn * 16 + (lane & 15);
          W[rowoff + col] = f2bf(acc[fm][fn][i] + b1v + c1v[fn]);
        }
      }
    }
  } else {
    // ---- quantize ----
    const int qb = blockIdx.x - 1024;
    float2 v2 = ((const float2*)part)[t];
    float mn = v2.x, mx = v2.y;
#pragma unroll
    for (int o = 32; o > 0; o >>= 1) {
      mn = fminf(mn, __shfl_down(mn, o));
      mx = fmaxf(mx, __shfl_down(mx, o));
    }
    __shared__ float smn2[4], smx2[4], ssc[1];
    int lane = t & 63, w = t >> 6;
    if (lane == 0) { smn2[w] = mn; smx2[w] = mx; }
    __syncthreads();
    if (t == 0) {
      mn = fminf(fminf(smn2[0], smn2[1]), fminf(smn2[2], smn2[3]));
      mx = fmaxf(fmaxf(smx2[0], smx2[1]), fmaxf(smx2[2], smx2[3]));
      ssc[0] = fmaxf((mx - mn) / 254.0f, 1e-8f);
      if (qb == 0) scl[0] = ssc[0];
    }
    __syncthreads();
    const float s = ssc[0];
    int i = qb * 256 + t;
    float4 v = ((const float4*)x)[i];
    float a = fminf(fmaxf(rintf(v.x / s), -127.f), 127.f);
    float b = fminf(fmaxf(rintf(v.y / s), -127.f), 127.f);
    float c = fminf(fmaxf(rintf(v.z / s), -127.f), 127.f);
    float d = fminf(fmaxf(rintf(v.w / s), -127.f), 127.f);
    ((ushort4*)xq)[i] = make_ushort4(f2bf(a), f2bf(b), f2bf(c), f2bf(d));
  }
}

// ---------------- 3) GEMM split-K8: BM=256,BN=256,BK=64; 8 waves 2x4, wave 128x64 ----------------
// Grid 256 = 8(sk==XCD) x 2(bm) x 16(bn). Each XCD owns one K-slice -> its 4MB W panel
// stays in its L2. LDS 2x64KB dbuf, counted vmcnt(8).
// ALL slices write bf16 partials in REGISTER-NATIVE layout: ushort4 per lane, 512B
// contiguous per store inst -> no 64B-sector write amplification (R6's +25MB defect).
__global__ __launch_bounds__(512) void k_gemm(const unsigned short* __restrict__ Xq,
                                              const unsigned short* __restrict__ W,
                                              unsigned short* __restrict__ P) {
  __shared__ unsigned short Al[2][256 * 64];  // 2 x 32KB
  __shared__ unsigned short Bl[2][256 * 64];  // 2 x 32KB
  const int t = threadIdx.x, lane = t & 63, wid = t >> 6;  // wid 0..7
  const int wg = (blockIdx.x & 7) * 32 + (blockIdx.x >> 3);  // bijective, 256%8==0
  const int sk = wg >> 5;        // 0..7 == XCD id -> W K-panel 4MB = its L2
  const int bm = (wg >> 4) & 1;  // 0..1
  const int bn = wg & 15;        // 0..15
  const int wm = wid >> 2, wn = wid & 3;  // wave tile 128x64 (2x4 waves)
  const int kbase = sk * 512;
  f32x4 acc[8][4];
#pragma unroll
  for (int a = 0; a < 8; ++a)
#pragma unroll
    for (int b = 0; b < 4; ++b) acc[a][b] = (f32x4)(0.f);

  const int lr = lane >> 3;         // row-in-chunk 0..7
  const int lcb = (lane & 7) * 16;  // byte col in 128B row

  auto STAGE = [&](int buf, int kt) {
    const int k0 = kbase + kt * 64;
#pragma unroll
    for (int c = 0; c < 4; ++c) {
      int chunk = wid * 4 + c;
      int r = chunk * 8 + lr;
      int colb = lcb ^ ((r & 7) << 4);
      load_lds16(Xq + ((size_t)(bm * 256 + r) << 12) + k0 + (colb >> 1), &Al[buf][chunk * 512]);
    }
#pragma unroll
    for (int c = 0; c < 4; ++c) {
      int chunk = wid * 4 + c;
      int r = chunk * 8 + lr;
      int colb = lcb ^ ((r & 7) << 4);
      load_lds16(W + ((size_t)(bn * 256 + r) << 12) + k0 + (colb >> 1), &Bl[buf][chunk * 512]);
    }
  };

  auto COMPUTE = [&](int buf) {
#pragma unroll
    for (int ks = 0; ks < 2; ++ks) {
      bf16x8 af[8], bfr[4];
#pragma unroll
      for (int fm = 0; fm < 8; ++fm) {
        int r = wm * 128 + fm * 16 + (lane & 15);
        int colb = (ks * 64 + ((lane >> 4) * 16)) ^ ((r & 7) << 4);
        af[fm] = *(const bf16x8*)((const char*)&Al[buf][0] + r * 128 + colb);
      }
#pragma unroll
      for (int fn = 0; fn < 4; ++fn) {
        int r = wn * 64 + fn * 16 + (lane & 15);
        int colb = (ks * 64 + ((lane >> 4) * 16)) ^ ((r & 7) << 4);
        bfr[fn] = *(const bf16x8*)((const char*)&Bl[buf][0] + r * 128 + colb);
      }
#pragma unroll
      for (int fm = 0; fm < 8; ++fm)
#pragma unroll
        for (int fn = 0; fn < 4; ++fn)
          acc[fm][fn] = __builtin_amdgcn_mfma_f32_16x16x32_bf16(af[fm], bfr[fn], acc[fm][fn], 0, 0, 0);
    }
  };

  STAGE(0, 0);  // prologue: 8 loads/wave outstanding
  for (int it = 0; it < 8; ++it) {
    STAGE((it + 1) & 1, (it + 1) & 7);  // it=7 restages kt=0 (dummy, never read)
    __builtin_amdgcn_sched_barrier(0);
    asm volatile("s_waitcnt vmcnt(8)" ::: "memory");  // stage(it) landed; 8 in flight
    __builtin_amdgcn_sched_barrier(0);
    __builtin_amdgcn_s_barrier();
    __builtin_amdgcn_sched_barrier(0);
    COMPUTE(it & 1);
    __builtin_amdgcn_sched_barrier(0);
    __builtin_amdgcn_s_barrier();
  }

  // register-native coalesced bf16 partial store:
  // idx = ((blkL*8 + wid)*32 + fm*4 + fn)*64 + lane   (512B contiguous per inst)
  unsigned short* Pk = P + (size_t)sk * 2097152;  // 4MB bytes per slice
  const int blkL = bm * 16 + bn;  // 0..31
#pragma unroll
  for (int fm = 0; fm < 8; ++fm) {
#pragma unroll
    for (int fn = 0; fn < 4; ++fn) {
      int idx = (((blkL * 8 + wid) * 32 + fm * 4 + fn) * 64) + lane;
      ushort4 o = make_ushort4(f2bf(acc[fm][fn][0]), f2bf(acc[fm][fn][1]),
                               f2bf(acc[fm][fn][2]), f2bf(acc[fm][fn][3]));
      ((ushort4*)Pk)[idx] = o;
    }
  }
}

// ---------------- 4) epilogue: out = (sum of 8 native-layout partials) * s + bias ----------------
__global__ __launch_bounds__(256) void k_epi(float* __restrict__ out,
                                             const unsigned short* __restrict__ P,
                                             const float* __restrict__ scl,
                                             const float* __restrict__ bias) {
  int g = blockIdx.x * 256 + threadIdx.x;  // 524288 threads, 4 elems each
  // invert: g = ((blkL*8 + wid)*32 + fm*4 + fn)*64 + lane
  const int lane = g & 63;
  const int ff = (g >> 6) & 31;
  const int fn = ff & 3, fm = ff >> 2;
  const int wid = (g >> 11) & 7;
  const int blkL = g >> 14;  // 0..31
  const int bm = blkL >> 4, bn = blkL & 15;
  const int wm = wid >> 2, wn = wid & 3;
  const int row0 = bm * 256 + wm * 128 + fm * 16 + ((lane >> 4) << 2);
  const int col = bn * 256 + wn * 64 + fn * 16 + (lane & 15);
  const float s = scl[0];
  const float bv = bias[col];
  float sum[4] = {0.f, 0.f, 0.f, 0.f};
#pragma unroll
  for (int k = 0; k < 8; ++k) {
    ushort4 p = ((const ushort4*)(P + (size_t)k * 2097152))[g];
    sum[0] += bf2f(p.x); sum[1] += bf2f(p.y); sum[2] += bf2f(p.z); sum[3] += bf2f(p.w);
  }
#pragma unroll
  for (int i = 0; i < 4; ++i) out[(size_t)(row0 + i) * 4096 + col] = sum[i] * s + bv;
}

// ---------------- fallback GEMM (used if ws too small for partials) ----------------
__global__ __launch_bounds__(512) void k_gemm_fb(const unsigned short* __restrict__ Xq,
                                                 const unsigned short* __restrict__ W,
                                                 const float* __restrict__ scl,
                                                 const float* __restrict__ bias,
                                                 float* __restrict__ out) {
  __shared__ unsigned short Al[4][128 * 64];
  __shared__ unsigned short Bl[4][64 * 64];
  const int t = threadIdx.x, lane = t & 63, wid = t >> 6;
  const int wg = (blockIdx.x & 7) * 32 + (blockIdx.x >> 3);
  const int bm = wg & 3;
  const int bn = wg >> 2;
  const int wm = wid >> 1, wn = wid & 1;
  f32x4 acc[2][2];
#pragma unroll
  for (int a = 0; a < 2; ++a)
#pragma unroll
    for (int b = 0; b < 2; ++b) acc[a][b] = (f32x4)(0.f);
  const int lr = lane >> 3;
  const int lcb = (lane & 7) * 16;
  auto STAGE = [&](int buf, int kt) {
    const int k0 = kt * 64;
#pragma unroll
    for (int c = 0; c < 2; ++c) {
      int chunk = wid * 2 + c;
      int r = chunk * 8 + lr;
      int colb = lcb ^ ((r & 7) << 4);
      load_lds16(Xq + ((size_t)(bm * 128 + r) << 12) + k0 + (colb >> 1), &Al[buf][chunk * 512]);
    }
    {
      int r = wid * 8 + lr;
      int colb = lcb ^ ((r & 7) << 4);
      load_lds16(W + ((size_t)(bn * 64 + r) << 12) + k0 + (colb >> 1), &Bl[buf][wid * 512]);
    }
  };
  auto COMPUTE = [&](int buf) {
#pragma unroll
    for (int ks = 0; ks < 2; ++ks) {
      bf16x8 af[2], bfr[2];
#pragma unroll
      for (int fm = 0; fm < 2; ++fm) {
        int r = wm * 32 + fm * 16 + (lane & 15);
        int colb = (ks * 64 + ((lane >> 4) * 16)) ^ ((r & 7) << 4);
        af[fm] = *(const bf16x8*)((const char*)&Al[buf][0] + r * 128 + colb);
      }
#pragma unroll
      for (int fn = 0; fn < 2; ++fn) {
        int r = wn * 32 + fn * 16 + (lane & 15);
        int colb = (ks * 64 + ((lane >> 4) * 16)) ^ ((r & 7) << 4);
        bfr[fn] = *(const bf16x8*)((const char*)&Bl[buf][0] + r * 128 + colb);
      }
#pragma unroll
      for (int fm = 0; fm < 2; ++fm)
#pragma unroll
        for (int fn = 0; fn < 2; ++fn)
          acc[fm][fn] = __builtin_amdgcn_mfma_f32_16x16x32_bf16(af[fm], bfr[fn], acc[fm][fn], 0, 0, 0);
    }
  };
  STAGE(0, 0); STAGE(1, 1); STAGE(2, 2);
  for (int t64 = 0; t64 < 64; ++t64) {
    STAGE((t64 + 3) & 3, (t64 + 3) & 63);
    __builtin_amdgcn_sched_barrier(0);
    asm volatile("s_waitcnt vmcnt(9)" ::: "memory");
    __builtin_amdgcn_sched_barrier(0);
    __builtin_amdgcn_s_barrier();
    __builtin_amdgcn_sched_barrier(0);
    COMPUTE(t64 & 3);
    __builtin_amdgcn_sched_barrier(0);
    __builtin_amdgcn_s_barrier();
  }
  const float s = scl[0];
#pragma unroll
  for (int fn = 0; fn < 2; ++fn) {
    int col = bn * 64 + wn * 32 + fn * 16 + (lane & 15);
    float bv = bias[col];
#pragma unroll
    for (int fm = 0; fm < 2; ++fm) {
#pragma unroll
      for (int i = 0; i < 4; ++i) {
        int row = bm * 128 + wm * 32 + fm * 16 + (lane >> 4) * 4 + i;
        out[(size_t)row * 4096 + col] = acc[fm][fn][i] * s + bv;
      }
    }
  }
}

extern "C" void kernel_launch(void* const* d_in, const int* in_sizes, int n_in,
                              void* d_out, int out_size, void* d_ws, size_t ws_size,
                              hipStream_t stream) {
  const float* x    = (const float*)d_in[0];  // (1,512,4096)
  const float* Ysg  = (const float*)d_in[1];  // (2,32,32,128,16)
  const float* Zsg  = (const float*)d_in[2];  // (2,32,32,16,128)
  const float* Ysc  = (const float*)d_in[3];  // (2,32,32)
  const float* Zsc  = (const float*)d_in[4];  // (2,32,32)
  const float* A    = (const float*)d_in[5];  // (2,32,32,4)
  const float* bias = (const float*)d_in[6];  // (4096,)
  float* out = (float*)d_out;

  char* ws = (char*)d_ws;
  float* scl  = (float*)ws;                  // [0] act_scale
  float* part = (float*)(ws + 256);          // 512 f32 partials
  unsigned short* Xq = (unsigned short*)(ws + 65536);                    // 4MB bf16
  unsigned short* W  = (unsigned short*)(ws + 65536 + (size_t)4194304);  // 32MB bf16
  unsigned short* P  = (unsigned short*)(ws + 65536 + (size_t)4194304 + (size_t)33554432);  // 32MB bf16 partials (8 slices)

  k_minmax_part<<<dim3(256), dim3(256), 0, stream>>>(x, part);
  k_fused<<<dim3(3072), dim3(256), 0, stream>>>(x, part, Ysg, Zsg, Ysc, Zsc, A, scl, Xq, W);
  if (ws_size >= (size_t)65536 + 4194304 + 33554432 + 33554432) {
    k_gemm<<<dim3(256), dim3(512), 0, stream>>>(Xq, W, P);
    k_epi<<<dim3(2048), dim3(256), 0, stream>>>(out, P, scl, bias);
  } else {
    k_gemm_fb<<<dim3(256), dim3(512), 0, stream>>>(Xq, W, scl, bias, out);
  }
}

// Round 12
// 53.760 us; speedup vs baseline: 1.3719x; 1.0333x over previous
//
#include <hip/hip_runtime.h>
#include <hip/hip_bf16.h>

// BQQ dims: P=2, J=32, K=32, M=128, L=16, N=128; B=512; in=kn=4096; out=jm=4096
typedef __attribute__((ext_vector_type(4))) float f32x4;
typedef __attribute__((ext_vector_type(8))) short bf16x8;
typedef __attribute__((ext_vector_type(4))) unsigned int u32x4;

#define GLOBAL_AS __attribute__((address_space(1)))
#define LDS_AS __attribute__((address_space(3)))

static __device__ __forceinline__ unsigned short f2bf(float f) {
  __hip_bfloat16 h = __float2bfloat16(f);
  return __builtin_bit_cast(unsigned short, h);
}
static __device__ __forceinline__ float bf2f(unsigned short u) {
  unsigned int v = ((unsigned int)u) << 16;
  return __builtin_bit_cast(float, v);
}
static __device__ __forceinline__ void load_lds16(const void* g, void* l) {
  __builtin_amdgcn_global_load_lds((GLOBAL_AS void*)g, (LDS_AS void*)l, 16, 0, 0);
}

// ---------------- 1) per-block min/max of input (2M f32), 256 blocks ----------------
__global__ __launch_bounds__(256) void k_minmax_part(const float* __restrict__ x,
                                                     float* __restrict__ part) {
  int tid = blockIdx.x * 256 + threadIdx.x;
  const float4* xv = (const float4*)x;
  float mn = 3.4e38f, mx = -3.4e38f;
#pragma unroll
  for (int rep = 0; rep < 8; ++rep) {
    float4 v = xv[tid + rep * 65536];
    mn = fminf(mn, fminf(fminf(v.x, v.y), fminf(v.z, v.w)));
    mx = fmaxf(mx, fmaxf(fmaxf(v.x, v.y), fmaxf(v.z, v.w)));
  }
#pragma unroll
  for (int o = 32; o > 0; o >>= 1) {
    mn = fminf(mn, __shfl_down(mn, o));
    mx = fmaxf(mx, __shfl_down(mx, o));
  }
  __shared__ float smn[4], smx[4];
  int lane = threadIdx.x & 63, w = threadIdx.x >> 6;
  if (lane == 0) { smn[w] = mn; smx[w] = mx; }
  __syncthreads();
  if (threadIdx.x == 0) {
    mn = fminf(fminf(smn[0], smn[1]), fminf(smn[2], smn[3]));
    mx = fmaxf(fmaxf(smx[0], smx[1]), fmaxf(smx[2], smx[3]));
    part[2 * blockIdx.x] = mn;
    part[2 * blockIdx.x + 1] = mx;
  }
}

// ---------------- 2) fused: blocks 0..1023 = build W (MFMA); 1024..3071 = quantize ----------------
__global__ __launch_bounds__(256) void k_fused(const float* __restrict__ x,
                                               const float* __restrict__ part,
                                               const float* __restrict__ Ysg,
                                               const float* __restrict__ Zsg,
                                               const float* __restrict__ Ysc,
                                               const float* __restrict__ Zsc,
                                               const float* __restrict__ Acoef,
                                               float* __restrict__ scl,
                                               unsigned short* __restrict__ xq,
                                               unsigned short* __restrict__ W) {
  const int t = threadIdx.x;
  if (blockIdx.x < 1024) {
    // ---- build_w (MFMA) ----
    const int jk = blockIdx.x;  // j*32+k
    __shared__ unsigned short Yb[2 * 128 * 24];  // [p*128+m][24] halves; data in [0..16)
    __shared__ unsigned short Zb[128 * 36];      // [n][36] halves; data pl in [0..32)
    __shared__ float B1p[2][128];
    __shared__ float C1[128];
    float cf0[2], cf2[2], cf4[2];
    float Dv;
    {
      float ys0 = Ysc[jk], zs0 = Zsc[jk], ys1 = Ysc[1024 + jk], zs1 = Zsc[1024 + jk];
      const float* A0p = Acoef + (size_t)jk * 4;
      const float* A1p = Acoef + (size_t)(1024 + jk) * 4;
      cf0[0] = A0p[0] * ys0 * zs0; cf0[1] = A1p[0] * ys1 * zs1;
      cf2[0] = A0p[1] * ys0;       cf2[1] = A1p[1] * ys1;
      cf4[0] = A0p[2] * zs0;       cf4[1] = A1p[2] * zs1;
      Dv = A0p[3] + A1p[3];
    }
#pragma unroll
    for (int rep = 0; rep < 4; ++rep) {
      int q = rep * 256 + t;
      int l0 = (q & 3) * 4, m = (q >> 2) & 127, p = q >> 9;
      float4 v = *(const float4*)(Ysg + (size_t)(p * 1024 + jk) * 2048 + m * 16 + l0);
      float s4 = v.x + v.y + v.z + v.w;
      s4 += __shfl_xor(s4, 1);
      s4 += __shfl_xor(s4, 2);
      if ((t & 3) == 0) B1p[p][m] = s4;
      float c0 = cf0[p];
      ushort4 o = make_ushort4(f2bf(c0 * v.x), f2bf(c0 * v.y), f2bf(c0 * v.z), f2bf(c0 * v.w));
      *(ushort4*)&Yb[(p * 128 + m) * 24 + l0] = o;
    }
#pragma unroll
    for (int rep = 0; rep < 4; ++rep) {
      int q = rep * 256 + t;
      int n0 = (q & 31) * 4, l = (q >> 5) & 15, p = q >> 9;
      float4 v = *(const float4*)(Zsg + (size_t)(p * 1024 + jk) * 2048 + l * 128 + n0);
      int pl = p * 16 + l;
      Zb[(n0 + 0) * 36 + pl] = f2bf(v.x);
      Zb[(n0 + 1) * 36 + pl] = f2bf(v.y);
      Zb[(n0 + 2) * 36 + pl] = f2bf(v.z);
      Zb[(n0 + 3) * 36 + pl] = f2bf(v.w);
    }
    __syncthreads();
    if (t < 128) {
      float s0 = 0.f, s1 = 0.f;
#pragma unroll
      for (int l = 0; l < 16; ++l) {
        s0 += bf2f(Zb[t * 36 + l]);
        s1 += bf2f(Zb[t * 36 + 16 + l]);
      }
      C1[t] = cf4[0] * s0 + cf4[1] * s1;
    }
    __syncthreads();
    const int lane = t & 63, wid = t >> 6;
    const int wm = wid >> 1, wn = wid & 1;
    const int grp = lane >> 4;
    bf16x8 af[4], bfr[4];
#pragma unroll
    for (int fm = 0; fm < 4; ++fm) {
      int m = wm * 64 + fm * 16 + (lane & 15);
      af[fm] = *(const bf16x8*)((const char*)Yb + ((grp >> 1) * 128 + m) * 48 + (grp & 1) * 16);
    }
#pragma unroll
    for (int fn = 0; fn < 4; ++fn) {
      int n = wn * 64 + fn * 16 + (lane & 15);
      const char* zp = (const char*)Zb + n * 72 + grp * 16;
      uint2 z0 = *(const uint2*)zp;
      uint2 z1 = *(const uint2*)(zp + 8);
      u32x4 zw; zw[0] = z0.x; zw[1] = z0.y; zw[2] = z1.x; zw[3] = z1.y;
      bfr[fn] = __builtin_bit_cast(bf16x8, zw);
    }
    f32x4 acc[4][4];
#pragma unroll
    for (int fm = 0; fm < 4; ++fm)
#pragma unroll
      for (int fn = 0; fn < 4; ++fn)
        acc[fm][fn] = __builtin_amdgcn_mfma_f32_16x16x32_bf16(af[fm], bfr[fn], (f32x4)(0.f), 0, 0, 0);
    const int j = jk >> 5, k = jk & 31;
    float c1v[4];
#pragma unroll
    for (int fn = 0; fn < 4; ++fn) c1v[fn] = C1[wn * 64 + fn * 16 + (lane & 15)];
#pragma unroll
    for (int fm = 0; fm < 4; ++fm) {
#pragma unroll
      for (int i = 0; i < 4; ++i) {
        int row = wm * 64 + fm * 16 + (grp)*4 + i;
        float b1v = cf2[0] * B1p[0][row] + cf2[1] * B1p[1][row] + Dv;
        size_t rowoff = (size_t)(j * 128 + row) * 4096 + (size_t)(k * 128);
#pragma unroll
        for (int fn = 0; fn < 4; ++fn) {
          int col = wn * 64 + fn * 16 + (lane & 15);
          W[rowoff + col] = f2bf(acc[fm][fn][i] + b1v + c1v[fn]);
        }
      }
    }
  } else {
    // ---- quantize ----
    const int qb = blockIdx.x - 1024;
    float2 v2 = ((const float2*)part)[t];
    float mn = v2.x, mx = v2.y;
#pragma unroll
    for (int o = 32; o > 0; o >>= 1) {
      mn = fminf(mn, __shfl_down(mn, o));
      mx = fmaxf(mx, __shfl_down(mx, o));
    }
    __shared__ float smn2[4], smx2[4], ssc[1];
    int lane = t & 63, w = t >> 6;
    if (lane == 0) { smn2[w] = mn; smx2[w] = mx; }
    __syncthreads();
    if (t == 0) {
      mn = fminf(fminf(smn2[0], smn2[1]), fminf(smn2[2], smn2[3]));
      mx = fmaxf(fmaxf(smx2[0], smx2[1]), fmaxf(smx2[2], smx2[3]));
      ssc[0] = fmaxf((mx - mn) / 254.0f, 1e-8f);
      if (qb == 0) scl[0] = ssc[0];
    }
    __syncthreads();
    const float s = ssc[0];
    int i = qb * 256 + t;
    float4 v = ((const float4*)x)[i];
    float a = fminf(fmaxf(rintf(v.x / s), -127.f), 127.f);
    float b = fminf(fmaxf(rintf(v.y / s), -127.f), 127.f);
    float c = fminf(fmaxf(rintf(v.z / s), -127.f), 127.f);
    float d = fminf(fmaxf(rintf(v.w / s), -127.f), 127.f);
    ((ushort4*)xq)[i] = make_ushort4(f2bf(a), f2bf(b), f2bf(c), f2bf(d));
  }
}

// ---------------- 3) GEMM split-K8: BM=256,BN=256,BK=64; 8 waves 2x4, wave 128x64 ----------------
// R11 geometry + T3/T5 phase-split inner loop:
//   issue A-stage(nxt); vmcnt(4) [prev iter's 8 done, 4 in flight]; barrier;
//   {ds_read ks0, issue B-stage(nxt)}; setprio(1) MFMA ks0 x32 setprio(0);
//   ds_read ks1; setprio(1) MFMA ks1 x32 setprio(0); barrier.
// Creates per-iter wave role-split (staging vs MFMA) so setprio can arbitrate
// across the 2 waves/SIMD. Buffer hazards identical to R11 (verified).
__global__ __launch_bounds__(512) void k_gemm(const unsigned short* __restrict__ Xq,
                                              const unsigned short* __restrict__ W,
                                              unsigned short* __restrict__ P) {
  __shared__ unsigned short Al[2][256 * 64];  // 2 x 32KB
  __shared__ unsigned short Bl[2][256 * 64];  // 2 x 32KB
  const int t = threadIdx.x, lane = t & 63, wid = t >> 6;  // wid 0..7
  const int wg = (blockIdx.x & 7) * 32 + (blockIdx.x >> 3);  // bijective, 256%8==0
  const int sk = wg >> 5;        // 0..7 == XCD id -> W K-panel 4MB = its L2
  const int bm = (wg >> 4) & 1;  // 0..1
  const int bn = wg & 15;        // 0..15
  const int wm = wid >> 2, wn = wid & 3;  // wave tile 128x64 (2x4 waves)
  const int kbase = sk * 512;
  f32x4 acc[8][4];
#pragma unroll
  for (int a = 0; a < 8; ++a)
#pragma unroll
    for (int b = 0; b < 4; ++b) acc[a][b] = (f32x4)(0.f);

  const int lr = lane >> 3;         // row-in-chunk 0..7
  const int lcb = (lane & 7) * 16;  // byte col in 128B row

  auto STAGE_A = [&](int buf, int kt) {
    const int k0 = kbase + kt * 64;
#pragma unroll
    for (int c = 0; c < 4; ++c) {
      int chunk = wid * 4 + c;
      int r = chunk * 8 + lr;
      int colb = lcb ^ ((r & 7) << 4);
      load_lds16(Xq + ((size_t)(bm * 256 + r) << 12) + k0 + (colb >> 1), &Al[buf][chunk * 512]);
    }
  };
  auto STAGE_B = [&](int buf, int kt) {
    const int k0 = kbase + kt * 64;
#pragma unroll
    for (int c = 0; c < 4; ++c) {
      int chunk = wid * 4 + c;
      int r = chunk * 8 + lr;
      int colb = lcb ^ ((r & 7) << 4);
      load_lds16(W + ((size_t)(bn * 256 + r) << 12) + k0 + (colb >> 1), &Bl[buf][chunk * 512]);
    }
  };

  // prologue: fill buf0 (8 loads/wave outstanding)
  STAGE_A(0, 0);
  STAGE_B(0, 0);
  for (int it = 0; it < 8; ++it) {
    const int cur = it & 1, nxt = cur ^ 1;
    const int ktn = (it + 1) & 7;  // it=7 restages kt=0 (dummy, never read)
    // ---- phase 0: issue next A, gate on prev tile landed ----
    STAGE_A(nxt, ktn);
    __builtin_amdgcn_sched_barrier(0);
    asm volatile("s_waitcnt vmcnt(4)" ::: "memory");  // prev 8 done; new 4 in flight
    __builtin_amdgcn_sched_barrier(0);
    __builtin_amdgcn_s_barrier();                     // buf[cur] ready for all waves
    __builtin_amdgcn_sched_barrier(0);
    // ---- phase 1: ds_read ks0 + issue next B, then MFMA cluster ----
    {
      bf16x8 af[8], bfr[4];
#pragma unroll
      for (int fm = 0; fm < 8; ++fm) {
        int r = wm * 128 + fm * 16 + (lane & 15);
        int colb = (((lane >> 4) * 16)) ^ ((r & 7) << 4);
        af[fm] = *(const bf16x8*)((const char*)&Al[cur][0] + r * 128 + colb);
      }
#pragma unroll
      for (int fn = 0; fn < 4; ++fn) {
        int r = wn * 64 + fn * 16 + (lane & 15);
        int colb = (((lane >> 4) * 16)) ^ ((r & 7) << 4);
        bfr[fn] = *(const bf16x8*)((const char*)&Bl[cur][0] + r * 128 + colb);
      }
      STAGE_B(nxt, ktn);  // overlaps with ds_read latency; outstanding -> 8
      __builtin_amdgcn_sched_barrier(0);
      __builtin_amdgcn_s_setprio(1);
#pragma unroll
      for (int fm = 0; fm < 8; ++fm)
#pragma unroll
        for (int fn = 0; fn < 4; ++fn)
          acc[fm][fn] = __builtin_amdgcn_mfma_f32_16x16x32_bf16(af[fm], bfr[fn], acc[fm][fn], 0, 0, 0);
      __builtin_amdgcn_s_setprio(0);
      __builtin_amdgcn_sched_barrier(0);
    }
    // ---- phase 2: ds_read ks1, MFMA cluster ----
    {
      bf16x8 af[8], bfr[4];
#pragma unroll
      for (int fm = 0; fm < 8; ++fm) {
        int r = wm * 128 + fm * 16 + (lane & 15);
        int colb = (64 + ((lane >> 4) * 16)) ^ ((r & 7) << 4);
        af[fm] = *(const bf16x8*)((const char*)&Al[cur][0] + r * 128 + colb);
      }
#pragma unroll
      for (int fn = 0; fn < 4; ++fn) {
        int r = wn * 64 + fn * 16 + (lane & 15);
        int colb = (64 + ((lane >> 4) * 16)) ^ ((r & 7) << 4);
        bfr[fn] = *(const bf16x8*)((const char*)&Bl[cur][0] + r * 128 + colb);
      }
      __builtin_amdgcn_sched_barrier(0);
      __builtin_amdgcn_s_setprio(1);
#pragma unroll
      for (int fm = 0; fm < 8; ++fm)
#pragma unroll
        for (int fn = 0; fn < 4; ++fn)
          acc[fm][fn] = __builtin_amdgcn_mfma_f32_16x16x32_bf16(af[fm], bfr[fn], acc[fm][fn], 0, 0, 0);
      __builtin_amdgcn_s_setprio(0);
      __builtin_amdgcn_sched_barrier(0);
    }
    __builtin_amdgcn_s_barrier();  // reads of cur done before next iter overwrites
  }

  // register-native coalesced bf16 partial store (512B contiguous per inst)
  unsigned short* Pk = P + (size_t)sk * 2097152;
  const int blkL = bm * 16 + bn;  // 0..31
#pragma unroll
  for (int fm = 0; fm < 8; ++fm) {
#pragma unroll
    for (int fn = 0; fn < 4; ++fn) {
      int idx = (((blkL * 8 + wid) * 32 + fm * 4 + fn) * 64) + lane;
      ushort4 o = make_ushort4(f2bf(acc[fm][fn][0]), f2bf(acc[fm][fn][1]),
                               f2bf(acc[fm][fn][2]), f2bf(acc[fm][fn][3]));
      ((ushort4*)Pk)[idx] = o;
    }
  }
}

// ---------------- 4) epilogue: out = (sum of 8 native-layout partials) * s + bias ----------------
__global__ __launch_bounds__(256) void k_epi(float* __restrict__ out,
                                             const unsigned short* __restrict__ P,
                                             const float* __restrict__ scl,
                                             const float* __restrict__ bias) {
  int g = blockIdx.x * 256 + threadIdx.x;  // 524288 threads, 4 elems each
  const int lane = g & 63;
  const int ff = (g >> 6) & 31;
  const int fn = ff & 3, fm = ff >> 2;
  const int wid = (g >> 11) & 7;
  const int blkL = g >> 14;  // 0..31
  const int bm = blkL >> 4, bn = blkL & 15;
  const int wm = wid >> 2, wn = wid & 3;
  const int row0 = bm * 256 + wm * 128 + fm * 16 + ((lane >> 4) << 2);
  const int col = bn * 256 + wn * 64 + fn * 16 + (lane & 15);
  const float s = scl[0];
  const float bv = bias[col];
  float sum[4] = {0.f, 0.f, 0.f, 0.f};
#pragma unroll
  for (int k = 0; k < 8; ++k) {
    ushort4 p = ((const ushort4*)(P + (size_t)k * 2097152))[g];
    sum[0] += bf2f(p.x); sum[1] += bf2f(p.y); sum[2] += bf2f(p.z); sum[3] += bf2f(p.w);
  }
#pragma unroll
  for (int i = 0; i < 4; ++i) out[(size_t)(row0 + i) * 4096 + col] = sum[i] * s + bv;
}

// ---------------- fallback GEMM (used if ws too small for partials) ----------------
__global__ __launch_bounds__(512) void k_gemm_fb(const unsigned short* __restrict__ Xq,
                                                 const unsigned short* __restrict__ W,
                                                 const float* __restrict__ scl,
                                                 const float* __restrict__ bias,
                                                 float* __restrict__ out) {
  __shared__ unsigned short Al[4][128 * 64];
  __shared__ unsigned short Bl[4][64 * 64];
  const int t = threadIdx.x, lane = t & 63, wid = t >> 6;
  const int wg = (blockIdx.x & 7) * 32 + (blockIdx.x >> 3);
  const int bm = wg & 3;
  const int bn = wg >> 2;
  const int wm = wid >> 1, wn = wid & 1;
  f32x4 acc[2][2];
#pragma unroll
  for (int a = 0; a < 2; ++a)
#pragma unroll
    for (int b = 0; b < 2; ++b) acc[a][b] = (f32x4)(0.f);
  const int lr = lane >> 3;
  const int lcb = (lane & 7) * 16;
  auto STAGE = [&](int buf, int kt) {
    const int k0 = kt * 64;
#pragma unroll
    for (int c = 0; c < 2; ++c) {
      int chunk = wid * 2 + c;
      int r = chunk * 8 + lr;
      int colb = lcb ^ ((r & 7) << 4);
      load_lds16(Xq + ((size_t)(bm * 128 + r) << 12) + k0 + (colb >> 1), &Al[buf][chunk * 512]);
    }
    {
      int r = wid * 8 + lr;
      int colb = lcb ^ ((r & 7) << 4);
      load_lds16(W + ((size_t)(bn * 64 + r) << 12) + k0 + (colb >> 1), &Bl[buf][wid * 512]);
    }
  };
  auto COMPUTE = [&](int buf) {
#pragma unroll
    for (int ks = 0; ks < 2; ++ks) {
      bf16x8 af[2], bfr[2];
#pragma unroll
      for (int fm = 0; fm < 2; ++fm) {
        int r = wm * 32 + fm * 16 + (lane & 15);
        int colb = (ks * 64 + ((lane >> 4) * 16)) ^ ((r & 7) << 4);
        af[fm] = *(const bf16x8*)((const char*)&Al[buf][0] + r * 128 + colb);
      }
#pragma unroll
      for (int fn = 0; fn < 2; ++fn) {
        int r = wn * 32 + fn * 16 + (lane & 15);
        int colb = (ks * 64 + ((lane >> 4) * 16)) ^ ((r & 7) << 4);
        bfr[fn] = *(const bf16x8*)((const char*)&Bl[buf][0] + r * 128 + colb);
      }
#pragma unroll
      for (int fm = 0; fm < 2; ++fm)
#pragma unroll
        for (int fn = 0; fn < 2; ++fn)
          acc[fm][fn] = __builtin_amdgcn_mfma_f32_16x16x32_bf16(af[fm], bfr[fn], acc[fm][fn], 0, 0, 0);
    }
  };
  STAGE(0, 0); STAGE(1, 1); STAGE(2, 2);
  for (int t64 = 0; t64 < 64; ++t64) {
    STAGE((t64 + 3) & 3, (t64 + 3) & 63);
    __builtin_amdgcn_sched_barrier(0);
    asm volatile("s_waitcnt vmcnt(9)" ::: "memory");
    __builtin_amdgcn_sched_barrier(0);
    __builtin_amdgcn_s_barrier();
    __builtin_amdgcn_sched_barrier(0);
    COMPUTE(t64 & 3);
    __builtin_amdgcn_sched_barrier(0);
    __builtin_amdgcn_s_barrier();
  }
  const float s = scl[0];
#pragma unroll
  for (int fn = 0; fn < 2; ++fn) {
    int col = bn * 64 + wn * 32 + fn * 16 + (lane & 15);
    float bv = bias[col];
#pragma unroll
    for (int fm = 0; fm < 2; ++fm) {
#pragma unroll
      for (int i = 0; i < 4; ++i) {
        int row = bm * 128 + wm * 32 + fm * 16 + (lane >> 4) * 4 + i;
        out[(size_t)row * 4096 + col] = acc[fm][fn][i] * s + bv;
      }
    }
  }
}

extern "C" void kernel_launch(void* const* d_in, const int* in_sizes, int n_in,
                              void* d_out, int out_size, void* d_ws, size_t ws_size,
                              hipStream_t stream) {
  const float* x    = (const float*)d_in[0];  // (1,512,4096)
  const float* Ysg  = (const float*)d_in[1];  // (2,32,32,128,16)
  const float* Zsg  = (const float*)d_in[2];  // (2,32,32,16,128)
  const float* Ysc  = (const float*)d_in[3];  // (2,32,32)
  const float* Zsc  = (const float*)d_in[4];  // (2,32,32)
  const float* A    = (const float*)d_in[5];  // (2,32,32,4)
  const float* bias = (const float*)d_in[6];  // (4096,)
  float* out = (float*)d_out;

  char* ws = (char*)d_ws;
  float* scl  = (float*)ws;                  // [0] act_scale
  float* part = (float*)(ws + 256);          // 512 f32 partials
  unsigned short* Xq = (unsigned short*)(ws + 65536);                    // 4MB bf16
  unsigned short* W  = (unsigned short*)(ws + 65536 + (size_t)4194304);  // 32MB bf16
  unsigned short* P  = (unsigned short*)(ws + 65536 + (size_t)4194304 + (size_t)33554432);  // 32MB bf16 partials (8 slices)

  k_minmax_part<<<dim3(256), dim3(256), 0, stream>>>(x, part);
  k_fused<<<dim3(3072), dim3(256), 0, stream>>>(x, part, Ysg, Zsg, Ysc, Zsc, A, scl, Xq, W);
  if (ws_size >= (size_t)65536 + 4194304 + 33554432 + 33554432) {
    k_gemm<<<dim3(256), dim3(512), 0, stream>>>(Xq, W, P);
    k_epi<<<dim3(2048), dim3(256), 0, stream>>>(out, P, scl, bias);
  } else {
    k_gemm_fb<<<dim3(256), dim3(512), 0, stream>>>(Xq, W, scl, bias, out);
  }
}